// Round 10
// baseline (159.631 us; speedup 1.0000x reference)
//
#include <hip/hip_runtime.h>
#include <hip/hip_bf16.h>
#include <hip/hip_fp16.h>

// B=16, S=100, D=8192, P=100, W=3
constexpr int Dk   = 8192;
constexpr int Bb   = 16;
constexpr int Ss   = 100;
constexpr int Pp   = 100;
constexpr int MROW = 1632;     // 16 * 102 padded rows
constexpr int NT   = 20;       // n-tiles of 16 -> 320 cols (q|k|v|20 zero)
constexpr int NCC  = 320;
constexpr int NQ   = 304;      // reduced qkv row stride (fp32)
constexpr int KG   = 1024;     // k-groups of 8 (K=8192)
constexpr int KC   = 16;       // K splits (chunk 512 = 4 groups of 4 steps)
constexpr int CH   = 5;        // attn positions per block
constexpr int MBL  = 52;       // m-blocks of 32 rows

constexpr size_t B_SEG   = (size_t)NT * KG * 128;   // shorts per B segment
constexpr size_t PSTRIDE = (size_t)1664 * NCC;      // halfs per part slice

typedef short s8v __attribute__((ext_vector_type(8)));
typedef short s4v __attribute__((ext_vector_type(4)));
typedef float f4v __attribute__((ext_vector_type(4)));

__device__ inline unsigned short f2bf_rne(float f) {
    unsigned u = __float_as_uint(f);
    u += 0x7fffu + ((u >> 16) & 1u);
    return (unsigned short)(u >> 16);
}

// Pack [wq|wk|wv|0] into hi/lo fragment layout [nt][kg][lane16][8].
// Thread = (kg, n-quad): 8 float4 loads, 8x16B writes. 320 blocks.
__global__ __launch_bounds__(256) void pack_b(
    const float* __restrict__ wq, const float* __restrict__ wk,
    const float* __restrict__ wv,
    short* __restrict__ b_hi, short* __restrict__ b_lo) {
    const int id = blockIdx.x * 256 + threadIdx.x;   // 81920 threads
    const int ng = id % 80;                          // n-quad 0..79
    const int kg = id / 80;
    if (kg >= KG) return;
    const int n0 = ng * 4;

    const float* w = nullptr; int p0 = 0;
    if (n0 < 100)      { w = wq; p0 = n0; }
    else if (n0 < 200) { w = wk; p0 = n0 - 100; }
    else if (n0 < 300) { w = wv; p0 = n0 - 200; }

    float4 vj[8];
    #pragma unroll
    for (int j = 0; j < 8; ++j) {
        if (w) vj[j] = *(const float4*)(w + (size_t)(kg * 8 + j) * Pp + p0);
        else   vj[j] = make_float4(0.f, 0.f, 0.f, 0.f);
    }

    #pragma unroll
    for (int t = 0; t < 4; ++t) {
        const int n = n0 + t;
        const float vv[8] = {vj[0].x + 0.f, vj[1].x, vj[2].x, vj[3].x,
                             vj[4].x, vj[5].x, vj[6].x, vj[7].x};
        // select component t
        s8v hi, lo;
        #pragma unroll
        for (int j = 0; j < 8; ++j) {
            const float v = (t == 0) ? (&vj[j].x)[0] : (t == 1) ? (&vj[j].x)[1]
                          : (t == 2) ? (&vj[j].x)[2] : (&vj[j].x)[3];
            const unsigned u = __float_as_uint(v);
            hi[j] = (short)(unsigned short)(u >> 16);                 // trunc split
            lo[j] = (short)f2bf_rne(v - __uint_as_float(u & 0xffff0000u));
        }
        (void)vv;
        const size_t doff = ((size_t)(n >> 4) * KG + kg) * 128 + (size_t)(n & 15) * 8;
        *(s8v*)(b_hi + doff) = hi;
        *(s8v*)(b_lo + doff) = lo;
    }
}

// Fused QKV GEMM. Grid (52 mb, 16 kc); 256 thr = 4 n-waves.
// Block tile 32(M) x 320(N); wave tile 32x80 (2 m-frags x 5 n-frags).
// K-chunk 512 = 4 GROUPS of 4 steps (128 k). One barrier per GROUP (4/block):
// A for group g+1 is loaded right after barrier g and only drained at
// barrier g+1 (a full group of MFMAs of cover). fp16 partials out.
__global__ __launch_bounds__(256, 2) void qkv_gemm(
    const float* __restrict__ x, const float* __restrict__ fpad,
    const float* __restrict__ bpad,
    const short* __restrict__ b_hi, const short* __restrict__ b_lo,
    unsigned short* __restrict__ part) {
    __shared__ __align__(16) short ahis[2][4096];   // [buf][step4][frag2][kg4][m16][8]
    __shared__ __align__(16) short alos[2][4096];

    const int mb   = blockIdx.x;         // 0..51
    const int kc   = blockIdx.y;         // 0..15
    const int tid  = threadIdx.x;
    const int w    = tid >> 6;           // nw 0..3
    const int l    = tid & 63;
    const int m    = l & 15;
    const int quad = l >> 4;

    // staging role: thread -> (row sr, k-offset skq*4); 4 steps per group
    const int sr  = tid >> 3;            // 0..31
    const int skq = tid & 7;             // 0..7
    const float* sp;
    {
        const int r = mb * 32 + sr;
        if (r >= MROW) sp = fpad;        // junk rows, never read downstream
        else {
            const int b = r / 102, rr = r - b * 102;
            if (rr == 0)        sp = fpad + (size_t)b * Dk;
            else if (rr == 101) sp = bpad + (size_t)b * Dk;
            else                sp = x + ((size_t)b * Ss + (rr - 1)) * Dk;
        }
        sp += kc * 512 + skq * 4;
    }
    const int woff = ((sr >> 4) * 4 + (skq >> 1)) * 128 + (sr & 15) * 8 + (skq & 1) * 4;

    f4v acc[2][5];
    #pragma unroll
    for (int i = 0; i < 2; ++i)
        #pragma unroll
        for (int j = 0; j < 5; ++j) {
            f4v z = {0.f, 0.f, 0.f, 0.f};
            acc[i][j] = z;
        }

    // preload group 0's A (4 steps x float4)
    float4 avA[4];
    #pragma unroll
    for (int st = 0; st < 4; ++st) avA[st] = *(const float4*)(sp + st * 32);

    #pragma unroll
    for (int g = 0; g < 4; ++g) {
        const int buf = g & 1;

        // convert + stage group g into LDS
        #pragma unroll
        for (int st = 0; st < 4; ++st) {
            const float vv[4] = {avA[st].x, avA[st].y, avA[st].z, avA[st].w};
            s4v h4, l4;
            #pragma unroll
            for (int jj = 0; jj < 4; ++jj) {
                const unsigned u = __float_as_uint(vv[jj]);
                h4[jj] = (short)(unsigned short)(u >> 16);
                l4[jj] = (short)f2bf_rne(vv[jj] - __uint_as_float(u & 0xffff0000u));
            }
            *(s4v*)&ahis[buf][st * 1024 + woff] = h4;
            *(s4v*)&alos[buf][st * 1024 + woff] = l4;
        }
        __syncthreads();   // publish group g (drains everything outstanding)

        // prefetch group g+1's A — drained only at NEXT barrier
        if (g < 3) {
            #pragma unroll
            for (int st = 0; st < 4; ++st)
                avA[st] = *(const float4*)(sp + (g + 1) * 128 + st * 32);
        }

        // 4 barrier-free steps: ds_read frags + B loads + 30 MFMA each
        #pragma unroll
        for (int st = 0; st < 4; ++st) {
            const int so = st * 1024;
            const s8v ah0 = *(const s8v*)&ahis[buf][so + (quad * 16 + m) * 8];
            const s8v ah1 = *(const s8v*)&ahis[buf][so + ((4 + quad) * 16 + m) * 8];
            const s8v al0 = *(const s8v*)&alos[buf][so + (quad * 16 + m) * 8];
            const s8v al1 = *(const s8v*)&alos[buf][so + ((4 + quad) * 16 + m) * 8];

            const int kg = kc * 64 + g * 16 + st * 4 + quad;
            #pragma unroll
            for (int j = 0; j < 5; ++j) {
                const size_t bo = ((size_t)(w * 5 + j) * KG + kg) * 128 + (size_t)m * 8;
                const s8v bh = *(const s8v*)(b_hi + bo);
                const s8v bl = *(const s8v*)(b_lo + bo);
                acc[0][j] = __builtin_amdgcn_mfma_f32_16x16x32_bf16(ah0, bh, acc[0][j], 0, 0, 0);
                acc[1][j] = __builtin_amdgcn_mfma_f32_16x16x32_bf16(ah1, bh, acc[1][j], 0, 0, 0);
                acc[0][j] = __builtin_amdgcn_mfma_f32_16x16x32_bf16(al0, bh, acc[0][j], 0, 0, 0);
                acc[1][j] = __builtin_amdgcn_mfma_f32_16x16x32_bf16(al1, bh, acc[1][j], 0, 0, 0);
                acc[0][j] = __builtin_amdgcn_mfma_f32_16x16x32_bf16(ah0, bl, acc[0][j], 0, 0, 0);
                acc[1][j] = __builtin_amdgcn_mfma_f32_16x16x32_bf16(ah1, bl, acc[1][j], 0, 0, 0);
            }
        }
        __syncthreads();   // group g's LDS reads complete before buf reuse (g+2)
    }

    // store fp16 partials, row-major [kc][row][col]
    unsigned short* __restrict__ pout = part + (size_t)kc * PSTRIDE;
    #pragma unroll
    for (int i = 0; i < 2; ++i) {
        #pragma unroll
        for (int j = 0; j < 5; ++j) {
            const int col  = (w * 5 + j) * 16 + m;
            const int row0 = mb * 32 + i * 16 + quad * 4;
            #pragma unroll
            for (int r = 0; r < 4; ++r)
                pout[(size_t)(row0 + r) * NCC + col] =
                    __half_as_ushort(__float2half(acc[i][j][r]));
        }
    }
}

// Reduce KC fp16 partial slices -> fp32 qkv (stride 304).
// Thread = (cell row x col-octet, k-quarter): 4x 16B loads + shfl combine.
__global__ __launch_bounds__(256) void reduce_k(
    const unsigned short* __restrict__ part, float* __restrict__ qkv) {
    const int id = blockIdx.x * 256 + threadIdx.x;  // 266240 threads
    const int cell = id >> 2, kq = id & 3;
    const int row = cell / 40, c8 = cell - row * 40;
    const int col0 = c8 * 8;
    const size_t base = (size_t)row * NCC + col0;

    float sum[8] = {0.f, 0.f, 0.f, 0.f, 0.f, 0.f, 0.f, 0.f};
    #pragma unroll
    for (int k4 = 0; k4 < 4; ++k4) {
        const s8v u = *(const s8v*)(part + (size_t)(kq * 4 + k4) * PSTRIDE + base);
        #pragma unroll
        for (int ii = 0; ii < 8; ++ii)
            sum[ii] += __half2float(__ushort_as_half((unsigned short)u[ii]));
    }
    // combine the 4 k-quarters (lanes differing in bits 0-1)
    #pragma unroll
    for (int mask = 1; mask < 4; mask <<= 1)
        #pragma unroll
        for (int ii = 0; ii < 8; ++ii)
            sum[ii] += __shfl_xor(sum[ii], mask);

    if (kq == 0 && col0 < NQ) {
        f4v a = {sum[0], sum[1], sum[2], sum[3]};
        f4v b = {sum[4], sum[5], sum[6], sum[7]};
        *(f4v*)(qkv + (size_t)row * NQ + col0)     = a;
        *(f4v*)(qkv + (size_t)row * NQ + col0 + 4) = b;
    }
}

// Attention on reduced fp32 qkv. Block = (b, chunk of 5 positions); grid 320.
__global__ __launch_bounds__(256) void attn3(
    const float* __restrict__ qkv, float* __restrict__ out) {
    const int blk = blockIdx.x;          // 0..319
    const int b  = blk / (Ss / CH);
    const int c  = blk % (Ss / CH);
    const int s0 = c * CH;
    const int tid = threadIdx.x;

    __shared__ float red[CH + 2][304];   // rows s0..s0+6
    __shared__ float sc[CH][3];

    // float4 loads (cols 300-303 are zero-filler, harmless)
    for (int idx = tid; idx < (CH + 2) * 76; idx += 256) {
        const int row = idx / 76, cg = idx % 76;
        *(f4v*)&red[row][cg * 4] =
            *(const f4v*)(qkv + (size_t)(b * 102 + s0 + row) * NQ + cg * 4);
    }
    __syncthreads();

    // 15 score dots, one per 16-lane group: (ss,u): Q[ss+1].K[ss+u]
    if (tid < CH * 3 * 16) {
        const int d = tid >> 4, g = tid & 15;
        const int ss = d / 3, u = d % 3;
        float ps = 0.0f;
        #pragma unroll
        for (int t = 0; t < 7; ++t) {
            const int p = g + t * 16;
            if (p < Pp) ps += red[ss + 1][p] * red[ss + u][100 + p];
        }
        #pragma unroll
        for (int off = 8; off > 0; off >>= 1) ps += __shfl_down(ps, off, 16);
        if (g == 0) sc[ss][u] = ps;
    }
    __syncthreads();

    for (int idx = tid; idx < CH * Pp; idx += 256) {
        const int ss = idx / Pp, p = idx % Pp;
        const float a0 = sc[ss][0], a1 = sc[ss][1], a2 = sc[ss][2];
        const float mx = fmaxf(a0, fmaxf(a1, a2));
        const float e0 = __expf(a0 - mx), e1 = __expf(a1 - mx), e2 = __expf(a2 - mx);
        const float inv = 1.0f / (e0 + e1 + e2);
        out[(size_t)(b * Ss + s0 + ss) * Pp + p] =
            inv * (e0 * red[ss][200 + p] + e1 * red[ss + 1][200 + p] +
                   e2 * red[ss + 2][200 + p]);
    }
}

extern "C" void kernel_launch(void* const* d_in, const int* in_sizes, int n_in,
                              void* d_out, int out_size, void* d_ws, size_t ws_size,
                              hipStream_t stream) {
    const float* x    = (const float*)d_in[0];
    const float* wq   = (const float*)d_in[1];
    const float* wk   = (const float*)d_in[2];
    const float* wv   = (const float*)d_in[3];
    const float* fpad = (const float*)d_in[4];
    const float* bpad = (const float*)d_in[5];
    float* out = (float*)d_out;

    short* b_hi = (short*)d_ws;                              // 5.24 MB
    short* b_lo = b_hi + B_SEG;                              // 5.24 MB
    unsigned short* part = (unsigned short*)(b_lo + B_SEG);  // 16*1664*320 fp16 = 17.0 MB
    float* qkv = (float*)(part + (size_t)KC * PSTRIDE);      // 1664*304 fp32 = 2.0 MB
    // total ws ~29.6 MB; all buffers fully overwritten, no zeroing needed

    pack_b<<<(KG * 80 + 255) / 256, 256, 0, stream>>>(wq, wk, wv, b_hi, b_lo);
    qkv_gemm<<<dim3(MBL, KC), 256, 0, stream>>>(x, fpad, bpad, b_hi, b_lo, part);
    reduce_k<<<(1664 * 40 * 4) / 256, 256, 0, stream>>>(part, qkv);
    attn3<<<Bb * (Ss / CH), 256, 0, stream>>>(qkv, out);
}